// Round 2
// baseline (113232.507 us; speedup 1.0000x reference)
//
#include <hip/hip_runtime.h>

// GRU scan T=512, B=128, H=512 fp32 — v4: persistent cooperative kernel,
// REGISTER-SPILL FIX over v3.
//
// v3 post-mortem: __launch_bounds__(512, 2) was interpreted as min-2-blocks/CU
// -> 128-VGPR cap, but live set = wreg(96) + acc(48) + temps ~= 175 floats
// -> ~50 VGPR spilled to scratch -> 267 GB HBM traffic/dispatch, VALUBusy 2.2%,
// 145 ms. v4 requests min 1 wave/EU -> 256-VGPR cap -> zero spill. Occupancy
// stays 1 wg/CU (110 KB LDS forces it), which cooperative co-residency needs.
//
// Structure (unchanged from v3):
//  - ONE cooperative kernel; 512 steps internally, device-wide monotonic
//    atomic barrier (counter in d_ws, release/acquire fences for XCD L2s).
//  - Weights in REGISTERS for the whole kernel: lane (w,kg,jl) owns
//    W[k-slice of 32][j0+jl][3 gates] = 96 VGPR. Zero steady-state W traffic.
//  - Per step only x_t, h_{t-1} move: coalesced f4 staging to LDS, read back
//    as 64B-contiguous f4 broadcasts (conflict-free).
//  - 8 waves: w0-3 h@Wh K-slices, w4-7 x@Wi K-slices; 1536 fmacs/lane/step.
//  - K-split partials -> f4 LDS reduction (stride-13 pad) overlaid on the
//    dead X/H tiles; 110 KB dynamic LDS -> exactly 1 wg/CU x 256 CUs.
//  - x[t+1] L2-prefetch overlapped with reduction + barrier wait.
// Predicted: VGPR ~180-210, FETCH+WRITE 267 GB -> <1.5 GB, VALUBusy 40-60%,
// dur_us 111710 -> ~2500-3500.

#define TT 512
#define BB 128
#define HH 512
#define H3 1536
#define NWG 256
#define NTHR 512

#define LDS_FLOATS 28160
#define LDS_BYTES  (LDS_FLOATS * 4)   // 112640 B <= 160 KiB
// float layout: Xs [0,8192) ; Hs [8192,16384) ; red (f4) overlays [0,26624) ;
//               sums [26624,28160)

__global__ __launch_bounds__(NTHR, 1) void gru_scan(
    const float* __restrict__ x,
    const float* __restrict__ h0,
    const float* __restrict__ Wi,
    const float* __restrict__ bi,
    const float* __restrict__ Wh,
    const float* __restrict__ bhn,
    float* out,
    unsigned int* __restrict__ bar)
{
  extern __shared__ float lds[];
  float*  Xs   = lds;
  float*  Hs   = lds + 8192;
  float4* red  = reinterpret_cast<float4*>(lds);
  float*  sums = lds + 26624;

  const int tid = threadIdx.x;
  const int n   = blockIdx.x;
  const int jt  = n & 31;            // 32 j-tiles of 16 cols
  const int bt  = n >> 5;            // 8 b-tiles of 16 rows
  const int j0  = jt * 16;
  const int b0  = bt * 16;

  const int w   = tid >> 6;          // wave 0..7 ; 0-3 -> h@Wh, 4-7 -> x@Wi
  const int kg  = (tid >> 4) & 3;
  const int jl  = tid & 15;
  const int kbase = (w & 3) * 128;   // K-slice of 128 per wave (per matrix)
  const bool isH = (w < 4);

  // ---- weights to registers: 96 VGPR/lane, loaded once for all 512 steps.
  // lane covers k = kbase + m*16 + kg*4 + kk (m 0..7, kk 0..3), col j0+jl, 3 gates.
  float wreg[8][4][3];
  {
    const float* __restrict__ W = isH ? Wh : Wi;
    #pragma unroll
    for (int m = 0; m < 8; ++m)
      #pragma unroll
      for (int kk = 0; kk < 4; ++kk) {
        const int k = kbase + m * 16 + kg * 4 + kk;
        #pragma unroll
        for (int g = 0; g < 3; ++g)
          wreg[m][kk][g] = W[(size_t)k * H3 + g * HH + j0 + jl];
      }
  }

  float* ys = out + BB * HH;

  // per-epilogue-thread constants hoisted out of the t-loop
  float bir = 0.f, biz = 0.f, bin = 0.f, bhnv = 0.f;
  if (tid < 256) {
    const int jj = j0 + (tid & 15);
    bir  = bi[jj];
    biz  = bi[jj + HH];
    bin  = bi[jj + 2 * HH];
    bhnv = bhn[jj];
  }

  for (int t = 0; t < TT; ++t) {
    const float* __restrict__ xt = x + (size_t)t * BB * HH;
    const float* hp = t ? (ys + (size_t)(t - 1) * BB * HH) : h0;

    // ---- stage x_t and h_{t-1} tiles (16 x 512 f each), coalesced f4 ----
    #pragma unroll
    for (int i = 0; i < 4; ++i) {
      const int idx = tid + i * NTHR;
      const int r = idx >> 7;        // 0..15
      const int c = idx & 127;       // f4 col
      const float4 xv = ((const float4*)(xt + (size_t)(b0 + r) * HH))[c];
      const float4 hv = ((const float4*)(hp + (size_t)(b0 + r) * HH))[c];
      *(float4*)&Xs[r * 512 + c * 4] = xv;
      *(float4*)&Hs[r * 512 + c * 4] = hv;
    }
    __syncthreads();

    // ---- GEMM slice: 1536 fmacs/lane, weights from registers -----------
    float acc[16][3];
    #pragma unroll
    for (int b = 0; b < 16; ++b)
      #pragma unroll
      for (int g = 0; g < 3; ++g) acc[b][g] = 0.f;

    {
      const float* __restrict__ S = isH ? Hs : Xs;
      #pragma unroll
      for (int m = 0; m < 8; ++m) {
        // per read instr: 4 distinct f4 (kg*16B) = one 64B line, 16-dup broadcast
        const float* Sm = S + kbase + m * 16 + kg * 4;
        #pragma unroll
        for (int bq = 0; bq < 4; ++bq) {
          const float4 v0 = *(const float4*)(Sm + (bq * 4 + 0) * 512);
          const float4 v1 = *(const float4*)(Sm + (bq * 4 + 1) * 512);
          const float4 v2 = *(const float4*)(Sm + (bq * 4 + 2) * 512);
          const float4 v3 = *(const float4*)(Sm + (bq * 4 + 3) * 512);
          #pragma unroll
          for (int g = 0; g < 3; ++g) {
            acc[bq*4+0][g] += v0.x*wreg[m][0][g] + v0.y*wreg[m][1][g] + v0.z*wreg[m][2][g] + v0.w*wreg[m][3][g];
            acc[bq*4+1][g] += v1.x*wreg[m][0][g] + v1.y*wreg[m][1][g] + v1.z*wreg[m][2][g] + v1.w*wreg[m][3][g];
            acc[bq*4+2][g] += v2.x*wreg[m][0][g] + v2.y*wreg[m][1][g] + v2.z*wreg[m][2][g] + v2.w*wreg[m][3][g];
            acc[bq*4+3][g] += v3.x*wreg[m][0][g] + v3.y*wreg[m][1][g] + v3.z*wreg[m][2][g] + v3.w*wreg[m][3][g];
          }
        }
      }
    }
    __syncthreads();   // Xs/Hs dead -> red may overlay them

    // ---- L2-prefetch next x tile (overlaps reduction + barrier wait) ----
    if (t + 1 < TT) {
      const float* xn = x + (size_t)(t + 1) * BB * HH;
      #pragma unroll
      for (int i = 0; i < 4; ++i) {
        const int idx = tid + i * NTHR;
        const int r = idx >> 7;
        const int c = idx & 127;
        const float4 v = ((const float4*)(xn + (size_t)(b0 + r) * HH))[c];
        asm volatile("" :: "v"(v.x), "v"(v.y), "v"(v.z), "v"(v.w));
      }
    }

    // ---- write K-split partials: 12 f4/lane, stride 13 breaks conflicts --
    {
      float4* rp = red + (size_t)(((w * 4 + kg) * 16) + jl) * 13;
      #pragma unroll
      for (int bq = 0; bq < 4; ++bq)
        #pragma unroll
        for (int g = 0; g < 3; ++g)
          rp[bq * 3 + g] = make_float4(acc[bq*4+0][g], acc[bq*4+1][g],
                                       acc[bq*4+2][g], acc[bq*4+3][g]);
    }
    __syncthreads();

    // ---- reduce the 16 partials per matrix (384 active threads) ---------
    {
      const int pm  = tid >> 8;        // 0 = h-side, 1 = x-side
      const int pjl = (tid >> 4) & 15;
      const int pg  = (tid >> 2) & 3;
      const int pbq = tid & 3;
      if (pg < 3) {
        float4 s = make_float4(0.f, 0.f, 0.f, 0.f);
        #pragma unroll
        for (int ww = 0; ww < 4; ++ww)
          #pragma unroll
          for (int k2 = 0; k2 < 4; ++k2) {
            const float4 v = red[(size_t)((((pm*4+ww)*4 + k2) * 16) + pjl) * 13 + pbq * 3 + pg];
            s.x += v.x; s.y += v.y; s.z += v.z; s.w += v.w;
          }
        *(float4*)&sums[(size_t)(((pm * 16 + pjl) * 3) + pg) * 16 + pbq * 4] = s;
      }
    }
    __syncthreads();

    // ---- fused gate epilogue + store h_t (256 threads, one (b,j) each) --
    if (tid < 256) {
      const int eb  = tid >> 4;
      const int jl2 = tid & 15;
      const int jj  = j0 + jl2;
      const float ghr = sums[(jl2*3 + 0)*16 + eb];
      const float ghz = sums[(jl2*3 + 1)*16 + eb];
      const float ghn = sums[(jl2*3 + 2)*16 + eb];
      const float gir = sums[((16 + jl2)*3 + 0)*16 + eb];
      const float giz = sums[((16 + jl2)*3 + 1)*16 + eb];
      const float gin = sums[((16 + jl2)*3 + 2)*16 + eb];

      const float gr = gir + ghr + bir;
      const float gz = giz + ghz + biz;
      const float r  = 1.f / (1.f + __expf(-gr));
      const float z  = 1.f / (1.f + __expf(-gz));
      const float pre = gin + bin + r * (ghn + bhnv);
      const float e2 = __expf(2.f * pre);
      const float nn = 1.f - 2.f / (e2 + 1.f);
      const float hpv = hp[(size_t)(b0 + eb) * HH + jj];   // L2-hot
      const float h = (1.f - z) * nn + z * hpv;

      const size_t o = (size_t)(b0 + eb) * HH + jj;
      ys[(size_t)t * BB * HH + o] = h;
      if (t == TT - 1) out[o] = h;
    }

    // ---- device-wide barrier: monotonic counter in d_ws -----------------
    if (t + 1 < TT) {
      __syncthreads();               // all stores of this wg issued & drained
      if (tid == 0) {
        __threadfence();             // release: write back XCD L2 (h_t visible)
        atomicAdd(bar, 1u);          // device-scope
        const unsigned int target = (unsigned int)NWG * (unsigned int)(t + 1);
        while (__hip_atomic_load(bar, __ATOMIC_ACQUIRE, __HIP_MEMORY_SCOPE_AGENT) < target)
          __builtin_amdgcn_s_sleep(2);
        __threadfence();             // acquire: invalidate L1/L2 before reads
      }
      __syncthreads();
    }
  }
}

extern "C" void kernel_launch(void* const* d_in, const int* in_sizes, int n_in,
                              void* d_out, int out_size, void* d_ws, size_t ws_size,
                              hipStream_t stream) {
  const float* x   = (const float*)d_in[0];  // [T,B,H]
  const float* h0  = (const float*)d_in[1];  // [B,H]
  const float* Wi  = (const float*)d_in[2];  // [H,3H]
  const float* bi  = (const float*)d_in[3];  // [3H]
  const float* Wh  = (const float*)d_in[4];  // [H,3H]
  const float* bhn = (const float*)d_in[5];  // [H]
  float* out = (float*)d_out;                // [B,H] final + [T,B,H] ys
  unsigned int* bar = (unsigned int*)d_ws;

  static bool attr_done = false;
  if (!attr_done) {
    hipFuncSetAttribute(reinterpret_cast<const void*>(gru_scan),
                        hipFuncAttributeMaxDynamicSharedMemorySize, LDS_BYTES);
    attr_done = true;
  }

  hipMemsetAsync(d_ws, 0, 64, stream);       // reset barrier counter each replay

  void* args[] = {(void*)&x, (void*)&h0, (void*)&Wi, (void*)&bi,
                  (void*)&Wh, (void*)&bhn, (void*)&out, (void*)&bar};
  hipLaunchCooperativeKernel(reinterpret_cast<const void*>(gru_scan),
                             dim3(NWG), dim3(NTHR), args, LDS_BYTES, stream);
}

// Round 3
// 111358.374 us; speedup vs baseline: 1.0168x; 1.0168x over previous
//
#include <hip/hip_runtime.h>

// GRU scan T=512, B=128, H=512 fp32 — v5: persistent cooperative kernel,
// STATIC-LDS fix for the register-budget cap.
//
// v3/v4 post-mortem: VGPR_Count pinned at 128 in BOTH runs regardless of
// __launch_bounds__ second arg; 117+143 GB of HBM traffic = scratch spill of
// the wreg(96)+acc(48) live set. Mechanism: LDS was DYNAMIC (extern __shared__)
// -> compile-time group_segment_size = 0 -> backend can't derive the real
// occupancy (1 wg/CU) and budgets registers for its default 4 waves/EU
// -> 128-VGPR cap -> ~45 floats spilled per lane per step.
// v5: static __shared__ float[28160] (110 KB) + amdgpu_waves_per_eu(2,2)
// -> compiler knows 2 waves/EU -> 256-VGPR budget -> zero spill.
//
// Structure (unchanged from v3/v4):
//  - ONE cooperative kernel; 512 steps, device-wide monotonic atomic barrier
//    (counter in d_ws, release/acquire fences for XCD L2s).
//  - Weights in REGISTERS for the whole kernel: lane (w,kg,jl) owns
//    W[k-slice of 32][j0+jl][3 gates] = 96 VGPR. Zero steady-state W traffic.
//  - Per step only x_t, h_{t-1} move: coalesced f4 staging to LDS, read back
//    as 64B-contiguous f4 broadcasts (conflict-free).
//  - 8 waves: w0-3 h@Wh K-slices, w4-7 x@Wi K-slices; 1536 fmacs/lane/step.
//  - K-split partials -> f4 LDS reduction (stride-13 pad) overlaid on the
//    dead X/H tiles; 110 KB LDS -> exactly 1 wg/CU x 256 CUs.
//  - x[t+1] L2-prefetch overlapped with reduction + barrier wait.
// Predicted: VGPR >=190, FETCH 117 GB -> <0.5 GB, WRITE 143 GB -> ~0.2 GB,
// VALUBusy 35-55%, dur_us 113232 -> ~1800-2800.

#define TT 512
#define BB 128
#define HH 512
#define H3 1536
#define NWG 256
#define NTHR 512

#define LDS_FLOATS 28160   // 112640 B <= 160 KiB
// float layout: Xs [0,8192) ; Hs [8192,16384) ; red (f4) overlays [0,26624) ;
//               sums [26624,28160)

__global__ __attribute__((amdgpu_waves_per_eu(2, 2)))
__launch_bounds__(NTHR) void gru_scan(
    const float* __restrict__ x,
    const float* __restrict__ h0,
    const float* __restrict__ Wi,
    const float* __restrict__ bi,
    const float* __restrict__ Wh,
    const float* __restrict__ bhn,
    float* out,
    unsigned int* __restrict__ bar)
{
  __shared__ float lds[LDS_FLOATS];
  float*  Xs   = lds;
  float*  Hs   = lds + 8192;
  float4* red  = reinterpret_cast<float4*>(lds);
  float*  sums = lds + 26624;

  const int tid = threadIdx.x;
  const int n   = blockIdx.x;
  const int jt  = n & 31;            // 32 j-tiles of 16 cols
  const int bt  = n >> 5;            // 8 b-tiles of 16 rows
  const int j0  = jt * 16;
  const int b0  = bt * 16;

  const int w   = tid >> 6;          // wave 0..7 ; 0-3 -> h@Wh, 4-7 -> x@Wi
  const int kg  = (tid >> 4) & 3;
  const int jl  = tid & 15;
  const int kbase = (w & 3) * 128;   // K-slice of 128 per wave (per matrix)
  const bool isH = (w < 4);

  // ---- weights to registers: 96 VGPR/lane, loaded once for all 512 steps.
  // lane covers k = kbase + m*16 + kg*4 + kk (m 0..7, kk 0..3), col j0+jl, 3 gates.
  float wreg[8][4][3];
  {
    const float* __restrict__ W = isH ? Wh : Wi;
    #pragma unroll
    for (int m = 0; m < 8; ++m)
      #pragma unroll
      for (int kk = 0; kk < 4; ++kk) {
        const int k = kbase + m * 16 + kg * 4 + kk;
        #pragma unroll
        for (int g = 0; g < 3; ++g)
          wreg[m][kk][g] = W[(size_t)k * H3 + g * HH + j0 + jl];
      }
  }

  float* ys = out + BB * HH;

  // per-epilogue-thread constants hoisted out of the t-loop
  float bir = 0.f, biz = 0.f, bin = 0.f, bhnv = 0.f;
  if (tid < 256) {
    const int jj = j0 + (tid & 15);
    bir  = bi[jj];
    biz  = bi[jj + HH];
    bin  = bi[jj + 2 * HH];
    bhnv = bhn[jj];
  }

  for (int t = 0; t < TT; ++t) {
    const float* __restrict__ xt = x + (size_t)t * BB * HH;
    const float* hp = t ? (ys + (size_t)(t - 1) * BB * HH) : h0;

    // ---- stage x_t and h_{t-1} tiles (16 x 512 f each), coalesced f4 ----
    #pragma unroll
    for (int i = 0; i < 4; ++i) {
      const int idx = tid + i * NTHR;
      const int r = idx >> 7;        // 0..15
      const int c = idx & 127;       // f4 col
      const float4 xv = ((const float4*)(xt + (size_t)(b0 + r) * HH))[c];
      const float4 hv = ((const float4*)(hp + (size_t)(b0 + r) * HH))[c];
      *(float4*)&Xs[r * 512 + c * 4] = xv;
      *(float4*)&Hs[r * 512 + c * 4] = hv;
    }
    __syncthreads();

    // ---- GEMM slice: 1536 fmacs/lane, weights from registers -----------
    float acc[16][3];
    #pragma unroll
    for (int b = 0; b < 16; ++b)
      #pragma unroll
      for (int g = 0; g < 3; ++g) acc[b][g] = 0.f;

    {
      const float* __restrict__ S = isH ? Hs : Xs;
      #pragma unroll
      for (int m = 0; m < 8; ++m) {
        // per read instr: 4 distinct f4 (kg*16B) = one 64B line, 16-dup broadcast
        const float* Sm = S + kbase + m * 16 + kg * 4;
        #pragma unroll
        for (int bq = 0; bq < 4; ++bq) {
          const float4 v0 = *(const float4*)(Sm + (bq * 4 + 0) * 512);
          const float4 v1 = *(const float4*)(Sm + (bq * 4 + 1) * 512);
          const float4 v2 = *(const float4*)(Sm + (bq * 4 + 2) * 512);
          const float4 v3 = *(const float4*)(Sm + (bq * 4 + 3) * 512);
          #pragma unroll
          for (int g = 0; g < 3; ++g) {
            acc[bq*4+0][g] += v0.x*wreg[m][0][g] + v0.y*wreg[m][1][g] + v0.z*wreg[m][2][g] + v0.w*wreg[m][3][g];
            acc[bq*4+1][g] += v1.x*wreg[m][0][g] + v1.y*wreg[m][1][g] + v1.z*wreg[m][2][g] + v1.w*wreg[m][3][g];
            acc[bq*4+2][g] += v2.x*wreg[m][0][g] + v2.y*wreg[m][1][g] + v2.z*wreg[m][2][g] + v2.w*wreg[m][3][g];
            acc[bq*4+3][g] += v3.x*wreg[m][0][g] + v3.y*wreg[m][1][g] + v3.z*wreg[m][2][g] + v3.w*wreg[m][3][g];
          }
        }
      }
    }
    __syncthreads();   // Xs/Hs dead -> red may overlay them

    // ---- L2-prefetch next x tile (overlaps reduction + barrier wait) ----
    if (t + 1 < TT) {
      const float* xn = x + (size_t)(t + 1) * BB * HH;
      #pragma unroll
      for (int i = 0; i < 4; ++i) {
        const int idx = tid + i * NTHR;
        const int r = idx >> 7;
        const int c = idx & 127;
        const float4 v = ((const float4*)(xn + (size_t)(b0 + r) * HH))[c];
        asm volatile("" :: "v"(v.x), "v"(v.y), "v"(v.z), "v"(v.w));
      }
    }

    // ---- write K-split partials: 12 f4/lane, stride 13 breaks conflicts --
    {
      float4* rp = red + (size_t)(((w * 4 + kg) * 16) + jl) * 13;
      #pragma unroll
      for (int bq = 0; bq < 4; ++bq)
        #pragma unroll
        for (int g = 0; g < 3; ++g)
          rp[bq * 3 + g] = make_float4(acc[bq*4+0][g], acc[bq*4+1][g],
                                       acc[bq*4+2][g], acc[bq*4+3][g]);
    }
    __syncthreads();

    // ---- reduce the 16 partials per matrix (384 active threads) ---------
    {
      const int pm  = tid >> 8;        // 0 = h-side, 1 = x-side
      const int pjl = (tid >> 4) & 15;
      const int pg  = (tid >> 2) & 3;
      const int pbq = tid & 3;
      if (pg < 3) {
        float4 s = make_float4(0.f, 0.f, 0.f, 0.f);
        #pragma unroll
        for (int ww = 0; ww < 4; ++ww)
          #pragma unroll
          for (int k2 = 0; k2 < 4; ++k2) {
            const float4 v = red[(size_t)((((pm*4+ww)*4 + k2) * 16) + pjl) * 13 + pbq * 3 + pg];
            s.x += v.x; s.y += v.y; s.z += v.z; s.w += v.w;
          }
        *(float4*)&sums[(size_t)(((pm * 16 + pjl) * 3) + pg) * 16 + pbq * 4] = s;
      }
    }
    __syncthreads();

    // ---- fused gate epilogue + store h_t (256 threads, one (b,j) each) --
    if (tid < 256) {
      const int eb  = tid >> 4;
      const int jl2 = tid & 15;
      const int jj  = j0 + jl2;
      const float ghr = sums[(jl2*3 + 0)*16 + eb];
      const float ghz = sums[(jl2*3 + 1)*16 + eb];
      const float ghn = sums[(jl2*3 + 2)*16 + eb];
      const float gir = sums[((16 + jl2)*3 + 0)*16 + eb];
      const float giz = sums[((16 + jl2)*3 + 1)*16 + eb];
      const float gin = sums[((16 + jl2)*3 + 2)*16 + eb];

      const float gr = gir + ghr + bir;
      const float gz = giz + ghz + biz;
      const float r  = 1.f / (1.f + __expf(-gr));
      const float z  = 1.f / (1.f + __expf(-gz));
      const float pre = gin + bin + r * (ghn + bhnv);
      const float e2 = __expf(2.f * pre);
      const float nn = 1.f - 2.f / (e2 + 1.f);
      const float hpv = hp[(size_t)(b0 + eb) * HH + jj];   // L2-hot
      const float h = (1.f - z) * nn + z * hpv;

      const size_t o = (size_t)(b0 + eb) * HH + jj;
      ys[(size_t)t * BB * HH + o] = h;
      if (t == TT - 1) out[o] = h;
    }

    // ---- device-wide barrier: monotonic counter in d_ws -----------------
    if (t + 1 < TT) {
      __syncthreads();               // all stores of this wg issued & drained
      if (tid == 0) {
        __threadfence();             // release: write back XCD L2 (h_t visible)
        atomicAdd(bar, 1u);          // device-scope
        const unsigned int target = (unsigned int)NWG * (unsigned int)(t + 1);
        while (__hip_atomic_load(bar, __ATOMIC_ACQUIRE, __HIP_MEMORY_SCOPE_AGENT) < target)
          __builtin_amdgcn_s_sleep(2);
        __threadfence();             // acquire: invalidate L1/L2 before reads
      }
      __syncthreads();
    }
  }
}

extern "C" void kernel_launch(void* const* d_in, const int* in_sizes, int n_in,
                              void* d_out, int out_size, void* d_ws, size_t ws_size,
                              hipStream_t stream) {
  const float* x   = (const float*)d_in[0];  // [T,B,H]
  const float* h0  = (const float*)d_in[1];  // [B,H]
  const float* Wi  = (const float*)d_in[2];  // [H,3H]
  const float* bi  = (const float*)d_in[3];  // [3H]
  const float* Wh  = (const float*)d_in[4];  // [H,3H]
  const float* bhn = (const float*)d_in[5];  // [H]
  float* out = (float*)d_out;                // [B,H] final + [T,B,H] ys
  unsigned int* bar = (unsigned int*)d_ws;

  hipMemsetAsync(d_ws, 0, 64, stream);       // reset barrier counter each replay

  void* args[] = {(void*)&x, (void*)&h0, (void*)&Wi, (void*)&bi,
                  (void*)&Wh, (void*)&bhn, (void*)&out, (void*)&bar};
  hipLaunchCooperativeKernel(reinterpret_cast<const void*>(gru_scan),
                             dim3(NWG), dim3(NTHR), args, 0, stream);
}

// Round 4
// 49877.203 us; speedup vs baseline: 2.2702x; 2.2327x over previous
//
#include <hip/hip_runtime.h>

// GRU scan T=512, B=128, H=512 fp32 — v6: fit the live set under the HARD
// 128-VGPR cap instead of fighting the register allocator.
//
// v3-v5 post-mortem: VGPR_Count pinned at 128 across launch_bounds(,2),
// launch_bounds(,1), static-LDS + amdgpu_waves_per_eu(2,2). Allocator never
// grants the 256-VGPR budget; wreg(96)+acc(48) live set spilled ~45 fl/lane
// -> 260 GB scratch HBM traffic, VALUBusy 2%. Fix: restructure so live<128:
//  - 1024 thr/wg (16 waves): wave = (matrix, K-slice of 64) -> wreg 96->48.
//  - GEMM streams one 4-row b-quad at a time: acc is a[4][3]=12 floats
//    (not 48); partial written out per-quad, never all live at once.
//  - kg 4-way K-split reduced IN-REGISTER: 2x shfl_xor(16,32) (DS crossbar,
//    no LDS storage), writer lane group kg==bq writes 3 f4 per quad.
//  - red buffer shrinks 106KB->53KB (256 rows x 13 f4, pad breaks banks),
//    DEDICATED region (no Xs/Hs overlay) -> one fewer WAR sync.
//  - 4 waves/SIMD (vs 2) doubles latency hiding on LDS broadcast reads.
// Everything else (persistent cooperative kernel, device barrier, weights
// resident in registers across all 512 steps, f4 staging, fused epilogue)
// unchanged from v5.
// Predicted: zero scratch: FETCH 117GB -> ~0.3GB, WRITE 143GB -> ~0.2GB,
// VALUBusy 2% -> 35-50%, dur_us 111358 -> ~2500-3500.

#define TT 512
#define BB 128
#define HH 512
#define H3 1536
#define NWG 256
#define NTHR 1024

// LDS floats: Xs [0,8192) ; Hs [8192,16384) ; red f4[256*13] = [16384,29696) ;
//             sums [29696,31232)  -> 124928 B <= 160 KiB, 1 wg/CU.
#define LDS_FLOATS 31232

__global__ __launch_bounds__(NTHR) void gru_scan(
    const float* __restrict__ x,
    const float* __restrict__ h0,
    const float* __restrict__ Wi,
    const float* __restrict__ bi,
    const float* __restrict__ Wh,
    const float* __restrict__ bhn,
    float* out,
    unsigned int* __restrict__ bar)
{
  __shared__ float lds[LDS_FLOATS];
  float*  Xs   = lds;
  float*  Hs   = lds + 8192;
  float4* red  = reinterpret_cast<float4*>(lds + 16384);
  float*  sums = lds + 29696;

  const int tid = threadIdx.x;
  const int n   = blockIdx.x;
  const int jt  = n & 31;            // 32 j-tiles of 16 cols
  const int bt  = n >> 5;            // 8 b-tiles of 16 rows
  const int j0  = jt * 16;
  const int b0  = bt * 16;

  const int w   = tid >> 6;          // wave 0..15 ; 0-7 -> h@Wh, 8-15 -> x@Wi
  const int kg  = (tid >> 4) & 3;    // 4-way K split within wave
  const int jl  = tid & 15;          // column within j-tile
  const int kbase = (w & 7) * 64;    // K-slice of 64 per wave (per matrix)
  const bool isH = (w < 8);

  // ---- weights to registers: 48 VGPR/lane, loaded once for all 512 steps.
  // lane covers k = kbase + m*16 + kg*4 + kk (m 0..3, kk 0..3), col j0+jl, 3 gates.
  float wreg[4][4][3];
  {
    const float* __restrict__ W = isH ? Wh : Wi;
    #pragma unroll
    for (int m = 0; m < 4; ++m)
      #pragma unroll
      for (int kk = 0; kk < 4; ++kk) {
        const int k = kbase + m * 16 + kg * 4 + kk;
        #pragma unroll
        for (int g = 0; g < 3; ++g)
          wreg[m][kk][g] = W[(size_t)k * H3 + g * HH + j0 + jl];
      }
  }

  float* ys = out + BB * HH;

  // per-epilogue-thread constants hoisted out of the t-loop
  float bir = 0.f, biz = 0.f, bin = 0.f, bhnv = 0.f;
  if (tid < 256) {
    const int jj = j0 + (tid & 15);
    bir  = bi[jj];
    biz  = bi[jj + HH];
    bin  = bi[jj + 2 * HH];
    bhnv = bhn[jj];
  }

  for (int t = 0; t < TT; ++t) {
    const float* __restrict__ xt = x + (size_t)t * BB * HH;
    const float* hp = t ? (ys + (size_t)(t - 1) * BB * HH) : h0;

    // ---- stage x_t and h_{t-1} tiles (16 x 512 f each), coalesced f4 ----
    #pragma unroll
    for (int i = 0; i < 2; ++i) {
      const int idx = tid + i * NTHR;   // 0..2047
      const int r = idx >> 7;           // 0..15
      const int c = idx & 127;          // f4 col
      const float4 xv = ((const float4*)(xt + (size_t)(b0 + r) * HH))[c];
      const float4 hv = ((const float4*)(hp + (size_t)(b0 + r) * HH))[c];
      *(float4*)&Xs[r * 512 + c * 4] = xv;
      *(float4*)&Hs[r * 512 + c * 4] = hv;
    }
    __syncthreads();

    // ---- GEMM: 768 fmacs/lane; one 4-row b-quad at a time (12 acc live) --
    {
      const float* __restrict__ S = isH ? Hs : Xs;
      #pragma unroll
      for (int bq = 0; bq < 4; ++bq) {
        float a[4][3];
        #pragma unroll
        for (int r = 0; r < 4; ++r)
          #pragma unroll
          for (int g = 0; g < 3; ++g) a[r][g] = 0.f;

        #pragma unroll
        for (int m = 0; m < 4; ++m) {
          // lanes of one wave read 4 distinct 16B lines (kg groups) of a 64B
          // span, broadcast to 16 jl lanes each -> conflict-free
          const float* Sm = S + kbase + m * 16 + kg * 4;
          const float4 v0 = *(const float4*)(Sm + (bq * 4 + 0) * 512);
          const float4 v1 = *(const float4*)(Sm + (bq * 4 + 1) * 512);
          const float4 v2 = *(const float4*)(Sm + (bq * 4 + 2) * 512);
          const float4 v3 = *(const float4*)(Sm + (bq * 4 + 3) * 512);
          #pragma unroll
          for (int g = 0; g < 3; ++g) {
            a[0][g] += v0.x*wreg[m][0][g] + v0.y*wreg[m][1][g] + v0.z*wreg[m][2][g] + v0.w*wreg[m][3][g];
            a[1][g] += v1.x*wreg[m][0][g] + v1.y*wreg[m][1][g] + v1.z*wreg[m][2][g] + v1.w*wreg[m][3][g];
            a[2][g] += v2.x*wreg[m][0][g] + v2.y*wreg[m][1][g] + v2.z*wreg[m][2][g] + v2.w*wreg[m][3][g];
            a[3][g] += v3.x*wreg[m][0][g] + v3.y*wreg[m][1][g] + v3.z*wreg[m][2][g] + v3.w*wreg[m][3][g];
          }
        }

        // in-register K reduction over the 4 kg groups (lanes ^16, ^32)
        #pragma unroll
        for (int r = 0; r < 4; ++r)
          #pragma unroll
          for (int g = 0; g < 3; ++g) {
            a[r][g] += __shfl_xor(a[r][g], 16);
            a[r][g] += __shfl_xor(a[r][g], 32);
          }

        // one kg group per quad writes the wave's finished partial
        if (kg == bq) {
          float4* rp = red + (size_t)(w * 16 + jl) * 13 + bq * 3;
          #pragma unroll
          for (int g = 0; g < 3; ++g)
            rp[g] = make_float4(a[0][g], a[1][g], a[2][g], a[3][g]);
        }
      }
    }

    // ---- L2-prefetch next x tile (overlaps reduction + barrier wait) ----
    if (t + 1 < TT) {
      const float* xn = x + (size_t)(t + 1) * BB * HH;
      #pragma unroll
      for (int i = 0; i < 2; ++i) {
        const int idx = tid + i * NTHR;
        const int r = idx >> 7;
        const int c = idx & 127;
        const float4 v = ((const float4*)(xn + (size_t)(b0 + r) * HH))[c];
        asm volatile("" :: "v"(v.x), "v"(v.y), "v"(v.z), "v"(v.w));
      }
    }
    __syncthreads();

    // ---- reduce the 8 wave-partials per matrix (384 active threads) ------
    {
      const int pm = tid >> 9;           // 0 = h-side, 1 = x-side
      const int t9 = tid & 511;
      const int pjl = (t9 >> 4) & 15;
      const int pg  = (t9 >> 2) & 3;
      const int pbq = t9 & 3;
      if ((t9 & 256) == 0 && pg < 3) {
        float4 s = make_float4(0.f, 0.f, 0.f, 0.f);
        #pragma unroll
        for (int w2 = 0; w2 < 8; ++w2) {
          const float4 v = red[(size_t)(pm * 128 + w2 * 16 + pjl) * 13 + pbq * 3 + pg];
          s.x += v.x; s.y += v.y; s.z += v.z; s.w += v.w;
        }
        *(float4*)&sums[(size_t)(((pm * 16 + pjl) * 3) + pg) * 16 + pbq * 4] = s;
      }
    }
    __syncthreads();

    // ---- fused gate epilogue + store h_t (256 threads, one (b,j) each) --
    if (tid < 256) {
      const int eb  = tid >> 4;
      const int jl2 = tid & 15;
      const int jj  = j0 + jl2;
      const float ghr = sums[(jl2*3 + 0)*16 + eb];
      const float ghz = sums[(jl2*3 + 1)*16 + eb];
      const float ghn = sums[(jl2*3 + 2)*16 + eb];
      const float gir = sums[((16 + jl2)*3 + 0)*16 + eb];
      const float giz = sums[((16 + jl2)*3 + 1)*16 + eb];
      const float gin = sums[((16 + jl2)*3 + 2)*16 + eb];

      const float gr = gir + ghr + bir;
      const float gz = giz + ghz + biz;
      const float r  = 1.f / (1.f + __expf(-gr));
      const float z  = 1.f / (1.f + __expf(-gz));
      const float pre = gin + bin + r * (ghn + bhnv);
      const float e2 = __expf(2.f * pre);
      const float nn = 1.f - 2.f / (e2 + 1.f);
      const float hpv = hp[(size_t)(b0 + eb) * HH + jj];   // L2-hot
      const float h = (1.f - z) * nn + z * hpv;

      const size_t o = (size_t)(b0 + eb) * HH + jj;
      ys[(size_t)t * BB * HH + o] = h;
      if (t == TT - 1) out[o] = h;
    }

    // ---- device-wide barrier: monotonic counter in d_ws -----------------
    if (t + 1 < TT) {
      __syncthreads();               // all stores of this wg issued & drained
      if (tid == 0) {
        __threadfence();             // release: write back XCD L2 (h_t visible)
        atomicAdd(bar, 1u);          // device-scope
        const unsigned int target = (unsigned int)NWG * (unsigned int)(t + 1);
        while (__hip_atomic_load(bar, __ATOMIC_ACQUIRE, __HIP_MEMORY_SCOPE_AGENT) < target)
          __builtin_amdgcn_s_sleep(2);
        __threadfence();             // acquire: invalidate before h reads
      }
      __syncthreads();
    }
  }
}

extern "C" void kernel_launch(void* const* d_in, const int* in_sizes, int n_in,
                              void* d_out, int out_size, void* d_ws, size_t ws_size,
                              hipStream_t stream) {
  const float* x   = (const float*)d_in[0];  // [T,B,H]
  const float* h0  = (const float*)d_in[1];  // [B,H]
  const float* Wi  = (const float*)d_in[2];  // [H,3H]
  const float* bi  = (const float*)d_in[3];  // [3H]
  const float* Wh  = (const float*)d_in[4];  // [H,3H]
  const float* bhn = (const float*)d_in[5];  // [H]
  float* out = (float*)d_out;                // [B,H] final + [T,B,H] ys
  unsigned int* bar = (unsigned int*)d_ws;

  hipMemsetAsync(d_ws, 0, 64, stream);       // reset barrier counter each replay

  void* args[] = {(void*)&x, (void*)&h0, (void*)&Wi, (void*)&bi,
                  (void*)&Wh, (void*)&bhn, (void*)&out, (void*)&bar};
  hipLaunchCooperativeKernel(reinterpret_cast<const void*>(gru_scan),
                             dim3(NWG), dim3(NTHR), args, 0, stream);
}

// Round 5
// 22541.786 us; speedup vs baseline: 5.0232x; 2.2127x over previous
//
#include <hip/hip_runtime.h>

// GRU scan T=512, B=128, H=512 fp32 — v7: weights banked in AGPRs (forced
// via inline asm), defeating the register allocator's 2-wg/CU spill heuristic.
//
// v6 post-mortem: VGPR_Count=64 (2-wg/CU budget; allocator ignores the 125KB
// LDS that caps us at 1 wg/CU). wreg[48] spilled: FETCH 108.8 GB matches
// 192 reloads/lane/step exactly; WRITE 20 GB = a[12] round-trip. Kernel is
// scratch-BW-bound (41 of 49.7 ms). Hints failed 4 rounds straight ->
// FORCE: v_accvgpr_write/read with "a" constraints pins the 48 weight floats
// in the (otherwise idle) AGPR file; allocator cannot spill them to meet its
// occupancy target, must step down a tier instead. + amdgpu_waves_per_eu(4,4).
// Peak pressure: 48 AGPR + ~60 VGPR ~= 108 <= 128-total tier at 4 waves/EU.
//
// Cost: 192 v_accvgpr_read/lane/step (1 VALU op each). VALU/step =
// (768 fmac + 192 read) x 2cy x 4 waves/SIMD = 7680 cy ~= 3.2 us + overhead.
// Structure otherwise identical to v6 (persistent cooperative kernel, 16
// waves = 2 matrices x 8 K-slices of 64, b-quad streaming, shfl_xor K-reduce,
// LDS partial reduce, fused gate epilogue, device-wide atomic barrier).
// Predicted: FETCH 1.09e8 -> <=5e6 KB, WRITE 2.0e7 -> ~3e5 KB,
// VALUBusy 5.7 -> 35-55%, dur_us 49877 -> ~2300-4000.

#define TT 512
#define BB 128
#define HH 512
#define H3 1536
#define NWG 256
#define NTHR 1024

// LDS floats: Xs [0,8192) ; Hs [8192,16384) ; red f4[256*13] = [16384,29696) ;
//             sums [29696,31232)  -> 124928 B <= 160 KiB, 1 wg/CU.
#define LDS_FLOATS 31232

__global__ __launch_bounds__(NTHR)
__attribute__((amdgpu_waves_per_eu(4, 4)))
void gru_scan(
    const float* __restrict__ x,
    const float* __restrict__ h0,
    const float* __restrict__ Wi,
    const float* __restrict__ bi,
    const float* __restrict__ Wh,
    const float* __restrict__ bhn,
    float* out,
    unsigned int* __restrict__ bar)
{
  __shared__ float lds[LDS_FLOATS];
  float*  Xs   = lds;
  float*  Hs   = lds + 8192;
  float4* red  = reinterpret_cast<float4*>(lds + 16384);
  float*  sums = lds + 29696;

  const int tid = threadIdx.x;
  const int n   = blockIdx.x;
  const int jt  = n & 31;            // 32 j-tiles of 16 cols
  const int bt  = n >> 5;            // 8 b-tiles of 16 rows
  const int j0  = jt * 16;
  const int b0  = bt * 16;

  const int w   = tid >> 6;          // wave 0..15 ; 0-7 -> h@Wh, 8-15 -> x@Wi
  const int kg  = (tid >> 4) & 3;    // 4-way K split within wave
  const int jl  = tid & 15;          // column within j-tile
  const int kbase = (w & 7) * 64;    // K-slice of 64 per wave (per matrix)
  const bool isH = (w < 8);

  // ---- weights -> AGPR bank: 48 regs/lane, written once for all 512 steps.
  // lane covers k = kbase + m*16 + kg*4 + kk (m 0..3, kk 0..3), col j0+jl,
  // 3 gates. index = (m*4+kk)*3 + g. Only "a"-constrained defs/uses -> the
  // values live in AGPRs; allocator cannot trade them for occupancy.
  float wa[48];
  {
    const float* __restrict__ W = isH ? Wh : Wi;
    #pragma unroll
    for (int m = 0; m < 4; ++m)
      #pragma unroll
      for (int kk = 0; kk < 4; ++kk) {
        const int k = kbase + m * 16 + kg * 4 + kk;
        #pragma unroll
        for (int g = 0; g < 3; ++g) {
          const float v = W[(size_t)k * H3 + g * HH + j0 + jl];
          asm volatile("v_accvgpr_write_b32 %0, %1"
                       : "=a"(wa[(m * 4 + kk) * 3 + g]) : "v"(v));
        }
      }
  }

  float* ys = out + BB * HH;

  // per-epilogue-thread constants hoisted out of the t-loop
  float bir = 0.f, biz = 0.f, bin = 0.f, bhnv = 0.f;
  if (tid < 256) {
    const int jj = j0 + (tid & 15);
    bir  = bi[jj];
    biz  = bi[jj + HH];
    bin  = bi[jj + 2 * HH];
    bhnv = bhn[jj];
  }

  for (int t = 0; t < TT; ++t) {
    const float* __restrict__ xt = x + (size_t)t * BB * HH;
    const float* hp = t ? (ys + (size_t)(t - 1) * BB * HH) : h0;

    // ---- stage x_t and h_{t-1} tiles (16 x 512 f each), coalesced f4 ----
    #pragma unroll
    for (int i = 0; i < 2; ++i) {
      const int idx = tid + i * NTHR;   // 0..2047
      const int r = idx >> 7;           // 0..15
      const int c = idx & 127;          // f4 col
      const float4 xv = ((const float4*)(xt + (size_t)(b0 + r) * HH))[c];
      const float4 hv = ((const float4*)(hp + (size_t)(b0 + r) * HH))[c];
      *(float4*)&Xs[r * 512 + c * 4] = xv;
      *(float4*)&Hs[r * 512 + c * 4] = hv;
    }
    __syncthreads();

    // ---- GEMM: 768 fmacs/lane; one 4-row b-quad at a time (12 acc live) --
    {
      const float* __restrict__ S = isH ? Hs : Xs;
      #pragma unroll
      for (int bq = 0; bq < 4; ++bq) {
        float a[4][3];
        #pragma unroll
        for (int r = 0; r < 4; ++r)
          #pragma unroll
          for (int g = 0; g < 3; ++g) a[r][g] = 0.f;

        #pragma unroll
        for (int m = 0; m < 4; ++m) {
          // pull this m's 12 weights AGPR->VGPR (fresh each bq: keeps live<128)
          float wv[12];
          #pragma unroll
          for (int kk = 0; kk < 4; ++kk)
            #pragma unroll
            for (int g = 0; g < 3; ++g)
              asm volatile("v_accvgpr_read_b32 %0, %1"
                           : "=v"(wv[kk * 3 + g])
                           : "a"(wa[(m * 4 + kk) * 3 + g]));

          // lanes of one wave read 4 distinct 16B lines (kg groups) of a 64B
          // span, broadcast to 16 jl lanes each -> conflict-free
          const float* Sm = S + kbase + m * 16 + kg * 4;
          const float4 v0 = *(const float4*)(Sm + (bq * 4 + 0) * 512);
          const float4 v1 = *(const float4*)(Sm + (bq * 4 + 1) * 512);
          const float4 v2 = *(const float4*)(Sm + (bq * 4 + 2) * 512);
          const float4 v3 = *(const float4*)(Sm + (bq * 4 + 3) * 512);
          #pragma unroll
          for (int g = 0; g < 3; ++g) {
            a[0][g] += v0.x*wv[0+g] + v0.y*wv[3+g] + v0.z*wv[6+g] + v0.w*wv[9+g];
            a[1][g] += v1.x*wv[0+g] + v1.y*wv[3+g] + v1.z*wv[6+g] + v1.w*wv[9+g];
            a[2][g] += v2.x*wv[0+g] + v2.y*wv[3+g] + v2.z*wv[6+g] + v2.w*wv[9+g];
            a[3][g] += v3.x*wv[0+g] + v3.y*wv[3+g] + v3.z*wv[6+g] + v3.w*wv[9+g];
          }
        }

        // in-register K reduction over the 4 kg groups (lanes ^16, ^32)
        #pragma unroll
        for (int r = 0; r < 4; ++r)
          #pragma unroll
          for (int g = 0; g < 3; ++g) {
            a[r][g] += __shfl_xor(a[r][g], 16);
            a[r][g] += __shfl_xor(a[r][g], 32);
          }

        // one kg group per quad writes the wave's finished partial
        if (kg == bq) {
          float4* rp = red + (size_t)(w * 16 + jl) * 13 + bq * 3;
          #pragma unroll
          for (int g = 0; g < 3; ++g)
            rp[g] = make_float4(a[0][g], a[1][g], a[2][g], a[3][g]);
        }
      }
    }

    // ---- L2-prefetch next x tile (overlaps reduction + barrier wait) ----
    if (t + 1 < TT) {
      const float* xn = x + (size_t)(t + 1) * BB * HH;
      #pragma unroll
      for (int i = 0; i < 2; ++i) {
        const int idx = tid + i * NTHR;
        const int r = idx >> 7;
        const int c = idx & 127;
        const float4 v = ((const float4*)(xn + (size_t)(b0 + r) * HH))[c];
        asm volatile("" :: "v"(v.x), "v"(v.y), "v"(v.z), "v"(v.w));
      }
    }
    __syncthreads();

    // ---- reduce the 8 wave-partials per matrix (384 active threads) ------
    {
      const int pm = tid >> 9;           // 0 = h-side, 1 = x-side
      const int t9 = tid & 511;
      const int pjl = (t9 >> 4) & 15;
      const int pg  = (t9 >> 2) & 3;
      const int pbq = t9 & 3;
      if ((t9 & 256) == 0 && pg < 3) {
        float4 s = make_float4(0.f, 0.f, 0.f, 0.f);
        #pragma unroll
        for (int w2 = 0; w2 < 8; ++w2) {
          const float4 v = red[(size_t)(pm * 128 + w2 * 16 + pjl) * 13 + pbq * 3 + pg];
          s.x += v.x; s.y += v.y; s.z += v.z; s.w += v.w;
        }
        *(float4*)&sums[(size_t)(((pm * 16 + pjl) * 3) + pg) * 16 + pbq * 4] = s;
      }
    }
    __syncthreads();

    // ---- fused gate epilogue + store h_t (256 threads, one (b,j) each) --
    if (tid < 256) {
      const int eb  = tid >> 4;
      const int jl2 = tid & 15;
      const int jj  = j0 + jl2;
      const float ghr = sums[(jl2*3 + 0)*16 + eb];
      const float ghz = sums[(jl2*3 + 1)*16 + eb];
      const float ghn = sums[(jl2*3 + 2)*16 + eb];
      const float gir = sums[((16 + jl2)*3 + 0)*16 + eb];
      const float giz = sums[((16 + jl2)*3 + 1)*16 + eb];
      const float gin = sums[((16 + jl2)*3 + 2)*16 + eb];

      const float gr = gir + ghr + bir;
      const float gz = giz + ghz + biz;
      const float r  = 1.f / (1.f + __expf(-gr));
      const float z  = 1.f / (1.f + __expf(-gz));
      const float pre = gin + bin + r * (ghn + bhnv);
      const float e2 = __expf(2.f * pre);
      const float nn = 1.f - 2.f / (e2 + 1.f);
      const float hpv = hp[(size_t)(b0 + eb) * HH + jj];   // L2-hot
      const float h = (1.f - z) * nn + z * hpv;

      const size_t o = (size_t)(b0 + eb) * HH + jj;
      ys[(size_t)t * BB * HH + o] = h;
      if (t == TT - 1) out[o] = h;
    }

    // ---- device-wide barrier: monotonic counter in d_ws -----------------
    if (t + 1 < TT) {
      __syncthreads();               // all stores of this wg issued & drained
      if (tid == 0) {
        __threadfence();             // release: write back XCD L2 (h_t visible)
        atomicAdd(bar, 1u);          // device-scope
        const unsigned int target = (unsigned int)NWG * (unsigned int)(t + 1);
        while (__hip_atomic_load(bar, __ATOMIC_ACQUIRE, __HIP_MEMORY_SCOPE_AGENT) < target)
          __builtin_amdgcn_s_sleep(2);
        __threadfence();             // acquire: invalidate before h reads
      }
      __syncthreads();
    }
  }
}

extern "C" void kernel_launch(void* const* d_in, const int* in_sizes, int n_in,
                              void* d_out, int out_size, void* d_ws, size_t ws_size,
                              hipStream_t stream) {
  const float* x   = (const float*)d_in[0];  // [T,B,H]
  const float* h0  = (const float*)d_in[1];  // [B,H]
  const float* Wi  = (const float*)d_in[2];  // [H,3H]
  const float* bi  = (const float*)d_in[3];  // [3H]
  const float* Wh  = (const float*)d_in[4];  // [H,3H]
  const float* bhn = (const float*)d_in[5];  // [H]
  float* out = (float*)d_out;                // [B,H] final + [T,B,H] ys
  unsigned int* bar = (unsigned int*)d_ws;

  hipMemsetAsync(d_ws, 0, 64, stream);       // reset barrier counter each replay

  void* args[] = {(void*)&x, (void*)&h0, (void*)&Wi, (void*)&bi,
                  (void*)&Wh, (void*)&bhn, (void*)&out, (void*)&bar};
  hipLaunchCooperativeKernel(reinterpret_cast<const void*>(gru_scan),
                             dim3(NWG), dim3(NTHR), args, 0, stream);
}

// Round 6
// 15736.357 us; speedup vs baseline: 7.1956x; 1.4325x over previous
//
#include <hip/hip_runtime.h>

// GRU scan T=512, B=128, H=512 fp32 — v8: kill the per-step L2 invalidate.
//
// v7 post-mortem: AGPR-banked weights fixed the spill (FETCH 108.8->7.7 GB,
// VGPR 64+48agpr). But 44 us/step @ VALUBusy 18.6%: still ~15 MB/step of
// re-fetch. Cause: the device barrier's __threadfence() pair -> acquire side
// emits a full L2 invalidate (buffer_inv) on every CU every step (XCD L2s are
// non-coherent, so a device-scope fence must drop clean lines) -> staged/
// prefetched x + all warm lines re-fetched through LLC each step, serialized
// behind the barrier.
// v8: surgical coherence instead of wholesale invalidation:
//  - ONLY h crosses wgs. h stores  = __hip_atomic_store(RELAXED, AGENT)
//    (write-through to LLC); h loads = __hip_atomic_load(RELAXED, AGENT)
//    (read-through, bypass stale L1/L2). NO threadfence anywhere -> x and
//    everything else stays L2-resident for all 512 steps.
//  - Barrier domain split 256 -> 8x32: rows b0..b0+15 only depend on the 32
//    wgs of the same b-tile. Per-group counters (128 B apart), release
//    fetch_add + relaxed poll. __syncthreads (vmcnt-draining) orders the
//    agent stores before tid0's release add.
//  - epilogue h_prev comes from the staged Hs tile in LDS (no global re-read).
// Everything else (AGPR weight bank, b-quad GEMM, shfl_xor K-reduce, LDS
// partial reduce, fused epilogue) unchanged from v7.
// Predicted: FETCH 7.7e6 -> ~4-5e6 KB (h-over-LLC remains, x-thrash gone),
// VALUBusy 18.6 -> 35-55%, dur_us 22542 -> ~6000-10000.

#define TT 512
#define BB 128
#define HH 512
#define H3 1536
#define NWG 256
#define NTHR 1024

// LDS floats: Xs [0,8192) ; Hs [8192,16384) ; red f4[256*13] = [16384,29696) ;
//             sums [29696,31232)  -> 124928 B <= 160 KiB, 1 wg/CU.
#define LDS_FLOATS 31232

__global__ __launch_bounds__(NTHR)
__attribute__((amdgpu_waves_per_eu(4, 4)))
void gru_scan(
    const float* __restrict__ x,
    const float* __restrict__ h0,
    const float* __restrict__ Wi,
    const float* __restrict__ bi,
    const float* __restrict__ Wh,
    const float* __restrict__ bhn,
    float* out,
    unsigned int* __restrict__ bars)
{
  __shared__ float lds[LDS_FLOATS];
  float*  Xs   = lds;
  float*  Hs   = lds + 8192;
  float4* red  = reinterpret_cast<float4*>(lds + 16384);
  float*  sums = lds + 29696;

  const int tid = threadIdx.x;
  const int n   = blockIdx.x;
  const int jt  = n & 31;            // 32 j-tiles of 16 cols
  const int bt  = n >> 5;            // 8 b-tiles of 16 rows -> barrier group
  const int j0  = jt * 16;
  const int b0  = bt * 16;

  const int w   = tid >> 6;          // wave 0..15 ; 0-7 -> h@Wh, 8-15 -> x@Wi
  const int kg  = (tid >> 4) & 3;    // 4-way K split within wave
  const int jl  = tid & 15;          // column within j-tile
  const int kbase = (w & 7) * 64;    // K-slice of 64 per wave (per matrix)
  const bool isH = (w < 8);

  unsigned int* grp = bars + bt * 32;  // per-b-group counter, 128 B apart

  // ---- weights -> AGPR bank: 48 regs/lane, written once for all 512 steps.
  float wa[48];
  {
    const float* __restrict__ W = isH ? Wh : Wi;
    #pragma unroll
    for (int m = 0; m < 4; ++m)
      #pragma unroll
      for (int kk = 0; kk < 4; ++kk) {
        const int k = kbase + m * 16 + kg * 4 + kk;
        #pragma unroll
        for (int g = 0; g < 3; ++g) {
          const float v = W[(size_t)k * H3 + g * HH + j0 + jl];
          asm volatile("v_accvgpr_write_b32 %0, %1"
                       : "=a"(wa[(m * 4 + kk) * 3 + g]) : "v"(v));
        }
      }
  }

  float* ys = out + BB * HH;

  // per-epilogue-thread constants hoisted out of the t-loop
  float bir = 0.f, biz = 0.f, bin = 0.f, bhnv = 0.f;
  if (tid < 256) {
    const int jj = j0 + (tid & 15);
    bir  = bi[jj];
    biz  = bi[jj + HH];
    bin  = bi[jj + 2 * HH];
    bhnv = bhn[jj];
  }

  for (int t = 0; t < TT; ++t) {
    const float* __restrict__ xt = x + (size_t)t * BB * HH;
    const float* hp = t ? (ys + (size_t)(t - 1) * BB * HH) : h0;

    // ---- stage h_{t-1}: agent-scope scalar loads (LLC-coherent), coalesced
    #pragma unroll
    for (int i = 0; i < 8; ++i) {
      const int idx = tid + i * NTHR;       // 0..8191
      const int r = idx >> 9;               // 0..15
      const int c = idx & 511;
      Hs[r * 512 + c] = __hip_atomic_load(
          const_cast<float*>(hp) + (size_t)(b0 + r) * HH + c,
          __ATOMIC_RELAXED, __HIP_MEMORY_SCOPE_AGENT);
    }
    // ---- stage x_t: plain f4 loads, L2-resident (prefetched, never inv'd)
    #pragma unroll
    for (int i = 0; i < 2; ++i) {
      const int idx = tid + i * NTHR;       // 0..2047
      const int r = idx >> 7;               // 0..15
      const int c = idx & 127;              // f4 col
      const float4 xv = ((const float4*)(xt + (size_t)(b0 + r) * HH))[c];
      *(float4*)&Xs[r * 512 + c * 4] = xv;
    }
    __syncthreads();

    // ---- GEMM: 768 fmacs/lane; one 4-row b-quad at a time (12 acc live) --
    {
      const float* __restrict__ S = isH ? Hs : Xs;
      #pragma unroll
      for (int bq = 0; bq < 4; ++bq) {
        float a[4][3];
        #pragma unroll
        for (int r = 0; r < 4; ++r)
          #pragma unroll
          for (int g = 0; g < 3; ++g) a[r][g] = 0.f;

        #pragma unroll
        for (int m = 0; m < 4; ++m) {
          // pull this m's 12 weights AGPR->VGPR
          float wv[12];
          #pragma unroll
          for (int kk = 0; kk < 4; ++kk)
            #pragma unroll
            for (int g = 0; g < 3; ++g)
              asm volatile("v_accvgpr_read_b32 %0, %1"
                           : "=v"(wv[kk * 3 + g])
                           : "a"(wa[(m * 4 + kk) * 3 + g]));

          const float* Sm = S + kbase + m * 16 + kg * 4;
          const float4 v0 = *(const float4*)(Sm + (bq * 4 + 0) * 512);
          const float4 v1 = *(const float4*)(Sm + (bq * 4 + 1) * 512);
          const float4 v2 = *(const float4*)(Sm + (bq * 4 + 2) * 512);
          const float4 v3 = *(const float4*)(Sm + (bq * 4 + 3) * 512);
          #pragma unroll
          for (int g = 0; g < 3; ++g) {
            a[0][g] += v0.x*wv[0+g] + v0.y*wv[3+g] + v0.z*wv[6+g] + v0.w*wv[9+g];
            a[1][g] += v1.x*wv[0+g] + v1.y*wv[3+g] + v1.z*wv[6+g] + v1.w*wv[9+g];
            a[2][g] += v2.x*wv[0+g] + v2.y*wv[3+g] + v2.z*wv[6+g] + v2.w*wv[9+g];
            a[3][g] += v3.x*wv[0+g] + v3.y*wv[3+g] + v3.z*wv[6+g] + v3.w*wv[9+g];
          }
        }

        // in-register K reduction over the 4 kg groups (lanes ^16, ^32)
        #pragma unroll
        for (int r = 0; r < 4; ++r)
          #pragma unroll
          for (int g = 0; g < 3; ++g) {
            a[r][g] += __shfl_xor(a[r][g], 16);
            a[r][g] += __shfl_xor(a[r][g], 32);
          }

        // one kg group per quad writes the wave's finished partial
        if (kg == bq) {
          float4* rp = red + (size_t)(w * 16 + jl) * 13 + bq * 3;
          #pragma unroll
          for (int g = 0; g < 3; ++g)
            rp[g] = make_float4(a[0][g], a[1][g], a[2][g], a[3][g]);
        }
      }
    }

    // ---- L2-prefetch next x tile (overlaps reduction + barrier wait) ----
    if (t + 1 < TT) {
      const float* xn = x + (size_t)(t + 1) * BB * HH;
      #pragma unroll
      for (int i = 0; i < 2; ++i) {
        const int idx = tid + i * NTHR;
        const int r = idx >> 7;
        const int c = idx & 127;
        const float4 v = ((const float4*)(xn + (size_t)(b0 + r) * HH))[c];
        asm volatile("" :: "v"(v.x), "v"(v.y), "v"(v.z), "v"(v.w));
      }
    }
    __syncthreads();

    // ---- reduce the 8 wave-partials per matrix (384 active threads) ------
    {
      const int pm = tid >> 9;           // 0 = h-side, 1 = x-side
      const int t9 = tid & 511;
      const int pjl = (t9 >> 4) & 15;
      const int pg  = (t9 >> 2) & 3;
      const int pbq = t9 & 3;
      if ((t9 & 256) == 0 && pg < 3) {
        float4 s = make_float4(0.f, 0.f, 0.f, 0.f);
        #pragma unroll
        for (int w2 = 0; w2 < 8; ++w2) {
          const float4 v = red[(size_t)(pm * 128 + w2 * 16 + pjl) * 13 + pbq * 3 + pg];
          s.x += v.x; s.y += v.y; s.z += v.z; s.w += v.w;
        }
        *(float4*)&sums[(size_t)(((pm * 16 + pjl) * 3) + pg) * 16 + pbq * 4] = s;
      }
    }
    __syncthreads();

    // ---- fused gate epilogue + store h_t (256 threads, one (b,j) each) --
    if (tid < 256) {
      const int eb  = tid >> 4;
      const int jl2 = tid & 15;
      const int jj  = j0 + jl2;
      const float ghr = sums[(jl2*3 + 0)*16 + eb];
      const float ghz = sums[(jl2*3 + 1)*16 + eb];
      const float ghn = sums[(jl2*3 + 2)*16 + eb];
      const float gir = sums[((16 + jl2)*3 + 0)*16 + eb];
      const float giz = sums[((16 + jl2)*3 + 1)*16 + eb];
      const float gin = sums[((16 + jl2)*3 + 2)*16 + eb];

      const float gr = gir + ghr + bir;
      const float gz = giz + ghz + biz;
      const float r  = 1.f / (1.f + __expf(-gr));
      const float z  = 1.f / (1.f + __expf(-gz));
      const float pre = gin + bin + r * (ghn + bhnv);
      const float e2 = __expf(2.f * pre);
      const float nn = 1.f - 2.f / (e2 + 1.f);
      const float hpv = Hs[eb * 512 + jj];           // staged h_{t-1} in LDS
      const float h = (1.f - z) * nn + z * hpv;

      const size_t o = (size_t)(b0 + eb) * HH + jj;
      // agent-scope write-through: visible at LLC, no fence/invalidate needed
      __hip_atomic_store(ys + (size_t)t * BB * HH + o, h,
                         __ATOMIC_RELAXED, __HIP_MEMORY_SCOPE_AGENT);
      if (t == TT - 1) out[o] = h;
    }

    // ---- per-b-group barrier (32 wgs): release add + relaxed poll --------
    if (t + 1 < TT) {
      __syncthreads();   // drains vmcnt -> all agent stores at LLC before add
      if (tid == 0) {
        __hip_atomic_fetch_add(grp, 1u, __ATOMIC_RELEASE,
                               __HIP_MEMORY_SCOPE_AGENT);
        const unsigned int target = 32u * (unsigned int)(t + 1);
        while (__hip_atomic_load(grp, __ATOMIC_RELAXED,
                                 __HIP_MEMORY_SCOPE_AGENT) < target)
          __builtin_amdgcn_s_sleep(1);
      }
      __syncthreads();
    }
  }
}

extern "C" void kernel_launch(void* const* d_in, const int* in_sizes, int n_in,
                              void* d_out, int out_size, void* d_ws, size_t ws_size,
                              hipStream_t stream) {
  const float* x   = (const float*)d_in[0];  // [T,B,H]
  const float* h0  = (const float*)d_in[1];  // [B,H]
  const float* Wi  = (const float*)d_in[2];  // [H,3H]
  const float* bi  = (const float*)d_in[3];  // [3H]
  const float* Wh  = (const float*)d_in[4];  // [H,3H]
  const float* bhn = (const float*)d_in[5];  // [H]
  float* out = (float*)d_out;                // [B,H] final + [T,B,H] ys
  unsigned int* bars = (unsigned int*)d_ws;  // 8 counters, 128 B apart

  hipMemsetAsync(d_ws, 0, 8 * 128, stream);  // reset group counters each replay

  void* args[] = {(void*)&x, (void*)&h0, (void*)&Wi, (void*)&bi,
                  (void*)&Wh, (void*)&bhn, (void*)&out, (void*)&bars};
  hipLaunchCooperativeKernel(reinterpret_cast<const void*>(gru_scan),
                             dim3(NWG), dim3(NTHR), args, 0, stream);
}